// Round 1
// baseline (1834.662 us; speedup 1.0000x reference)
//
#include <hip/hip_runtime.h>
#include <math.h>

#define V_N 100000
#define E_N 300000
#define D_N 128
#define EPSV 1e-5f
#define NCHUNK 391   // ceil(V_N/256)
#define BM 32
#define KH 64        // K half for LDS staging

// ----------------- CSR build -----------------
__global__ __launch_bounds__(256) void k_count(const int* __restrict__ edges, int* __restrict__ deg) {
  int i = blockIdx.x * blockDim.x + threadIdx.x;
  if (i < 2 * E_N) atomicAdd(&deg[edges[i]], 1);
}

__global__ __launch_bounds__(256) void k_chunksum(const int* __restrict__ deg, int* __restrict__ csum) {
  __shared__ int red[256];
  int c = blockIdx.x, t = threadIdx.x;
  int i = c * 256 + t;
  red[t] = (i < V_N) ? deg[i] : 0;
  __syncthreads();
  for (int s = 128; s > 0; s >>= 1) {
    if (t < s) red[t] += red[t + s];
    __syncthreads();
  }
  if (t == 0) csum[c] = red[0];
}

__global__ __launch_bounds__(512) void k_scanchunks(const int* __restrict__ csum, int* __restrict__ coff) {
  __shared__ int sh[512];
  int t = threadIdx.x;
  int v = (t < NCHUNK) ? csum[t] : 0;
  sh[t] = v;
  __syncthreads();
  for (int s = 1; s < 512; s <<= 1) {
    int x = (t >= s) ? sh[t - s] : 0;
    __syncthreads();
    sh[t] += x;
    __syncthreads();
  }
  if (t < NCHUNK) coff[t] = sh[t] - v;  // exclusive
}

__global__ __launch_bounds__(256) void k_writeoff(const int* __restrict__ deg, const int* __restrict__ coff,
                                                  int* __restrict__ csr_off, float* __restrict__ dinv) {
  __shared__ int sh[256];
  int c = blockIdx.x, t = threadIdx.x;
  int i = c * 256 + t;
  int v = (i < V_N) ? deg[i] : 0;
  sh[t] = v;
  __syncthreads();
  for (int s = 1; s < 256; s <<= 1) {
    int x = (t >= s) ? sh[t - s] : 0;
    __syncthreads();
    sh[t] += x;
    __syncthreads();
  }
  int excl = sh[t] - v;
  if (i <= V_N) csr_off[i] = coff[c] + excl;
  if (i < V_N) dinv[i] = 1.0f / (1.0f + (float)v);
}

__global__ __launch_bounds__(256) void k_fill(const int* __restrict__ edges, const int* __restrict__ csr_off,
                                              int* __restrict__ cursor, int* __restrict__ adj) {
  int e = blockIdx.x * blockDim.x + threadIdx.x;
  if (e >= E_N) return;
  int s = edges[2 * e], d = edges[2 * e + 1];
  int p = atomicAdd(&cursor[s], 1);
  adj[csr_off[s] + p] = d;
  int q = atomicAdd(&cursor[d], 1);
  adj[csr_off[d] + q] = s;
}

// ----------------- GEMM (+ optional gather/normalize) -----------------
// out = act(x) @ W^T + b           (MODE 0)
// out = dinv * (act(x)@W^T + b + sum_neighbors h1)   (MODE 1, in-place-safe on x==out)
// act(x) = aff ? relu(scale*x + shift) : x
template <int MODE>
__global__ __launch_bounds__(256) void k_gemm(
    const float* __restrict__ x, const float* __restrict__ W, const float* __restrict__ bvec,
    const float* __restrict__ scale, const float* __restrict__ shift, int aff,
    const float* __restrict__ h1, const int* __restrict__ csr_off, const int* __restrict__ adj,
    const float* __restrict__ dinv, float* __restrict__ out) {
  __shared__ float As[BM][KH + 4];
  __shared__ float Bs[D_N][KH + 4];
  int tid = threadIdx.x;
  int row0 = blockIdx.x * BM;
  int tr = tid >> 5, tc = tid & 31;
  int r0 = tr * 4, c0 = tc * 4;
  float acc[4][4] = {};

  for (int kh = 0; kh < D_N; kh += KH) {
    // stage x rows (apply deferred BN affine + relu of previous layer)
#pragma unroll
    for (int jj = 0; jj < 2; ++jj) {
      int q = jj * 256 + tid;          // 32 rows x 16 float4-chunks
      int r = q >> 4, kq = (q & 15) * 4;
      float4 xv = *(const float4*)&x[(size_t)(row0 + r) * D_N + kh + kq];
      if (aff) {
        float4 sc = *(const float4*)&scale[kh + kq];
        float4 sf = *(const float4*)&shift[kh + kq];
        xv.x = fmaxf(sc.x * xv.x + sf.x, 0.f);
        xv.y = fmaxf(sc.y * xv.y + sf.y, 0.f);
        xv.z = fmaxf(sc.z * xv.z + sf.z, 0.f);
        xv.w = fmaxf(sc.w * xv.w + sf.w, 0.f);
      }
      *(float4*)&As[r][kq] = xv;
    }
    // stage W half (row-major)
#pragma unroll
    for (int jj = 0; jj < 8; ++jj) {
      int q = jj * 256 + tid;          // 128 rows x 16 chunks
      int d = q >> 4, kq = (q & 15) * 4;
      *(float4*)&Bs[d][kq] = *(const float4*)&W[(size_t)d * D_N + kh + kq];
    }
    __syncthreads();

#pragma unroll
    for (int kk = 0; kk < KH; kk += 4) {
      float4 a[4], b[4];
#pragma unroll
      for (int i = 0; i < 4; ++i) a[i] = *(const float4*)&As[r0 + i][kk];
#pragma unroll
      for (int j = 0; j < 4; ++j) b[j] = *(const float4*)&Bs[c0 + j][kk];
#pragma unroll
      for (int i = 0; i < 4; ++i)
#pragma unroll
        for (int j = 0; j < 4; ++j) {
          acc[i][j] += a[i].x * b[j].x;
          acc[i][j] += a[i].y * b[j].y;
          acc[i][j] += a[i].z * b[j].z;
          acc[i][j] += a[i].w * b[j].w;
        }
    }
    __syncthreads();
  }

  float4 bv = *(const float4*)&bvec[c0];
  if (MODE == 0) {
#pragma unroll
    for (int i = 0; i < 4; ++i) {
      int v = row0 + r0 + i;
      float4 o;
      o.x = acc[i][0] + bv.x;
      o.y = acc[i][1] + bv.y;
      o.z = acc[i][2] + bv.z;
      o.w = acc[i][3] + bv.w;
      *(float4*)&out[(size_t)v * D_N + c0] = o;
    }
  } else {
#pragma unroll
    for (int i = 0; i < 4; ++i) {
      int v = row0 + r0 + i;
      float4 agg = {0.f, 0.f, 0.f, 0.f};
      int s = csr_off[v], e = csr_off[v + 1];
      for (int p = s; p < e; ++p) {
        int u = adj[p];
        float4 h = *(const float4*)&h1[(size_t)u * D_N + c0];
        agg.x += h.x; agg.y += h.y; agg.z += h.z; agg.w += h.w;
      }
      float di = dinv[v];
      float4 o;
      o.x = di * (acc[i][0] + bv.x + agg.x);
      o.y = di * (acc[i][1] + bv.y + agg.y);
      o.z = di * (acc[i][2] + bv.z + agg.z);
      o.w = di * (acc[i][3] + bv.w + agg.w);
      *(float4*)&out[(size_t)v * D_N + c0] = o;
    }
  }
}

// ----------------- BN stats over rows -----------------
__global__ __launch_bounds__(256) void k_stats(const float* __restrict__ t, float* __restrict__ stats) {
  __shared__ float red[512];
  int tid = threadIdx.x;
  int c = tid & 127, half = tid >> 7;
  float s = 0.f, sq = 0.f;
  for (int v = blockIdx.x * 2 + half; v < V_N; v += 512) {
    float val = t[(size_t)v * D_N + c];
    s += val;
    sq += val * val;
  }
  red[tid] = s;
  red[256 + tid] = sq;
  __syncthreads();
  if (half == 0) {
    atomicAdd(&stats[c], red[c] + red[128 + c]);
    atomicAdd(&stats[128 + c], red[256 + c] + red[256 + 128 + c]);
  }
}

__global__ void k_finalize(const float* __restrict__ stats, const float* __restrict__ gamma,
                           const float* __restrict__ beta, float* __restrict__ scale,
                           float* __restrict__ shift) {
  int d = threadIdx.x;
  float mu = stats[d] * (1.0f / V_N);
  float var = stats[128 + d] * (1.0f / V_N) - mu * mu;
  float g = gamma[d];
  float sc = g * rsqrtf(var + EPSV);
  scale[d] = sc;
  shift[d] = beta[d] - mu * sc;
}

// ----------------- final: out = relu(scale*t + shift + features) -----------------
__global__ __launch_bounds__(256) void k_final(const float* __restrict__ t, const float* __restrict__ feat,
                                               const float* __restrict__ scale, const float* __restrict__ shift,
                                               float* __restrict__ out) {
  int q = blockIdx.x * blockDim.x + threadIdx.x;  // float4 index
  if (q >= V_N * D_N / 4) return;
  int c4 = q & 31;
  float4 tv = ((const float4*)t)[q];
  float4 fv = ((const float4*)feat)[q];
  float4 sc = ((const float4*)scale)[c4];
  float4 sf = ((const float4*)shift)[c4];
  float4 o;
  o.x = fmaxf(sc.x * tv.x + sf.x + fv.x, 0.f);
  o.y = fmaxf(sc.y * tv.y + sf.y + fv.y, 0.f);
  o.z = fmaxf(sc.z * tv.z + sf.z + fv.z, 0.f);
  o.w = fmaxf(sc.w * tv.w + sf.w + fv.w, 0.f);
  ((float4*)out)[q] = o;
}

extern "C" void kernel_launch(void* const* d_in, const int* in_sizes, int n_in,
                              void* d_out, int out_size, void* d_ws, size_t ws_size,
                              hipStream_t stream) {
  const float* features = (const float*)d_in[0];
  const int* edges = (const int*)d_in[1];
  const float* W0 = (const float*)d_in[2];
  const float* b0 = (const float*)d_in[3];
  const float* W1 = (const float*)d_in[4];
  const float* b1 = (const float*)d_in[5];
  const float* gamma = (const float*)d_in[6];
  const float* beta = (const float*)d_in[7];
  float* out = (float*)d_out;

  char* ws = (char*)d_ws;
  size_t off = 0;
  auto alloc = [&](size_t bytes) -> void* {
    void* p = ws + off;
    off = (off + bytes + 255) & ~(size_t)255;
    return p;
  };
  int* deg = (int*)alloc((size_t)V_N * 4);
  int* csr_off = (int*)alloc((size_t)(V_N + 1) * 4);
  int* adj = (int*)alloc((size_t)2 * E_N * 4);
  float* dinv = (float*)alloc((size_t)V_N * 4);
  int* csum = (int*)alloc(512 * 4);
  int* coff = (int*)alloc(512 * 4);
  float* stats = (float*)alloc(256 * 4);
  float* scale = (float*)alloc(128 * 4);
  float* shift = (float*)alloc(128 * 4);
  float* h1 = (float*)alloc((size_t)V_N * D_N * 4);

  // CSR + dinv
  hipMemsetAsync(deg, 0, (size_t)V_N * 4, stream);
  k_count<<<(2 * E_N + 255) / 256, 256, 0, stream>>>(edges, deg);
  k_chunksum<<<NCHUNK, 256, 0, stream>>>(deg, csum);
  k_scanchunks<<<1, 512, 0, stream>>>(csum, coff);
  k_writeoff<<<NCHUNK, 256, 0, stream>>>(deg, coff, csr_off, dinv);
  hipMemsetAsync(deg, 0, (size_t)V_N * 4, stream);
  k_fill<<<(E_N + 255) / 256, 256, 0, stream>>>(edges, csr_off, deg, adj);

  const float* x = features;
  for (int l = 0; l < 3; ++l) {
    int aff = (l > 0) ? 1 : 0;
    k_gemm<0><<<V_N / BM, 256, 0, stream>>>(x, W1 + (size_t)l * D_N * D_N, b1 + l * D_N,
                                            scale, shift, aff,
                                            nullptr, nullptr, nullptr, nullptr, h1);
    k_gemm<1><<<V_N / BM, 256, 0, stream>>>(x, W0 + (size_t)l * D_N * D_N, b0 + l * D_N,
                                            scale, shift, aff,
                                            h1, csr_off, adj, dinv, out);
    hipMemsetAsync(stats, 0, 256 * 4, stream);
    k_stats<<<256, 256, 0, stream>>>(out, stats);
    k_finalize<<<1, 128, 0, stream>>>(stats, gamma + l * D_N, beta + l * D_N, scale, shift);
    x = out;  // next layer reads pre-BN t, applies affine+relu on the fly
  }
  k_final<<<(V_N * D_N / 4 + 255) / 256, 256, 0, stream>>>(out, features, scale, shift, out);
}

// Round 2
// 641.008 us; speedup vs baseline: 2.8622x; 2.8622x over previous
//
#include <hip/hip_runtime.h>
#include <math.h>
#include <stdint.h>

#define V_N 100000
#define E_N 300000
#define D_N 128
#define EPSV 1e-5f
#define NCHUNK 391   // ceil(V_N/256)
#define MPAD 100096  // 782 * 128

typedef _Float16 f16;
typedef f16 f16x8 __attribute__((ext_vector_type(8)));
typedef f16 f16x4 __attribute__((ext_vector_type(4)));
typedef f16 f16x2 __attribute__((ext_vector_type(2)));
typedef float f32x4 __attribute__((ext_vector_type(4)));

// ----------------- CSR build -----------------
__global__ __launch_bounds__(256) void k_count(const int* __restrict__ edges, int* __restrict__ deg) {
  int i = blockIdx.x * blockDim.x + threadIdx.x;
  if (i < 2 * E_N) atomicAdd(&deg[edges[i]], 1);
}

__global__ __launch_bounds__(256) void k_chunksum(const int* __restrict__ deg, int* __restrict__ csum) {
  __shared__ int red[256];
  int c = blockIdx.x, t = threadIdx.x;
  int i = c * 256 + t;
  red[t] = (i < V_N) ? deg[i] : 0;
  __syncthreads();
  for (int s = 128; s > 0; s >>= 1) {
    if (t < s) red[t] += red[t + s];
    __syncthreads();
  }
  if (t == 0) csum[c] = red[0];
}

__global__ __launch_bounds__(512) void k_scanchunks(const int* __restrict__ csum, int* __restrict__ coff) {
  __shared__ int sh[512];
  int t = threadIdx.x;
  int v = (t < NCHUNK) ? csum[t] : 0;
  sh[t] = v;
  __syncthreads();
  for (int s = 1; s < 512; s <<= 1) {
    int x = (t >= s) ? sh[t - s] : 0;
    __syncthreads();
    sh[t] += x;
    __syncthreads();
  }
  if (t < NCHUNK) coff[t] = sh[t] - v;  // exclusive
}

__global__ __launch_bounds__(256) void k_writeoff(const int* __restrict__ deg, const int* __restrict__ coff,
                                                  int* __restrict__ csr_off, float* __restrict__ dinv,
                                                  float* __restrict__ degf) {
  __shared__ int sh[256];
  int c = blockIdx.x, t = threadIdx.x;
  int i = c * 256 + t;
  int v = (i < V_N) ? deg[i] : 0;
  sh[t] = v;
  __syncthreads();
  for (int s = 1; s < 256; s <<= 1) {
    int x = (t >= s) ? sh[t - s] : 0;
    __syncthreads();
    sh[t] += x;
    __syncthreads();
  }
  int excl = sh[t] - v;
  if (i <= V_N) csr_off[i] = coff[c] + excl;
  if (i < V_N) {
    dinv[i] = 1.0f / (1.0f + (float)v);
    degf[i] = (float)v;
  }
}

__global__ __launch_bounds__(256) void k_fill(const int* __restrict__ edges, const int* __restrict__ csr_off,
                                              int* __restrict__ cursor, int* __restrict__ adj) {
  int e = blockIdx.x * blockDim.x + threadIdx.x;
  if (e >= E_N) return;
  int s = edges[2 * e], d = edges[2 * e + 1];
  int p = atomicAdd(&cursor[s], 1);
  adj[csr_off[s] + p] = d;
  int q = atomicAdd(&cursor[d], 1);
  adj[csr_off[d] + q] = s;
}

// ----------------- weight prep: Wcat[l][n][k] half, k = [W0 row | W1 row] -----------------
__global__ __launch_bounds__(256) void k_prepw(const float* __restrict__ W0, const float* __restrict__ W1,
                                               f16* __restrict__ Wc) {
  int idx = blockIdx.x * 256 + threadIdx.x;
  if (idx >= 3 * 128 * 256) return;
  int l = idx >> 15;
  int rem = idx & 32767;
  int n = rem >> 8, k = rem & 255;
  float v = (k < 128) ? W0[l * 16384 + n * 128 + k] : W1[l * 16384 + n * 128 + (k - 128)];
  Wc[idx] = (f16)v;
}

// ----------------- activation: ycat[v][0:128] = f16(act(x[v])) -----------------
__global__ __launch_bounds__(256) void k_act(const float* __restrict__ x, const float* __restrict__ scale,
                                             const float* __restrict__ shift, int aff, f16* __restrict__ ycat) {
  int q = blockIdx.x * 256 + threadIdx.x;  // float4 index over V_N*128
  if (q >= V_N * 32) return;
  int v = q >> 5, c4 = q & 31;
  float4 xv = ((const float4*)x)[q];
  if (aff) {
    float4 sc = ((const float4*)scale)[c4];
    float4 sf = ((const float4*)shift)[c4];
    xv.x = fmaxf(sc.x * xv.x + sf.x, 0.f);
    xv.y = fmaxf(sc.y * xv.y + sf.y, 0.f);
    xv.z = fmaxf(sc.z * xv.z + sf.z, 0.f);
    xv.w = fmaxf(sc.w * xv.w + sf.w, 0.f);
  }
  f16x4 h;
  h[0] = (f16)xv.x; h[1] = (f16)xv.y; h[2] = (f16)xv.z; h[3] = (f16)xv.w;
  *(f16x4*)&ycat[(size_t)v * 256 + c4 * 4] = h;
}

// ----------------- gather: ycat[v][128:256] = f16(sum_{u in N(v)} ycat[u][0:128]) -----------------
__global__ __launch_bounds__(256) void k_gather(f16* ycat, const int* __restrict__ csr_off,
                                                const int* __restrict__ adj) {
  int w = threadIdx.x >> 6, lane = threadIdx.x & 63;
  int v = blockIdx.x * 4 + w;
  if (v >= V_N) return;
  int s = csr_off[v], e = csr_off[v + 1];
  float a0 = 0.f, a1 = 0.f;
  for (int p = s; p < e; ++p) {
    int u = adj[p];
    f16x2 h = *(const f16x2*)&ycat[(size_t)u * 256 + lane * 2];
    a0 += (float)h[0];
    a1 += (float)h[1];
  }
  f16x2 o;
  o[0] = (f16)a0;
  o[1] = (f16)a1;
  *(f16x2*)&ycat[(size_t)v * 256 + 128 + lane * 2] = o;
}

// ----------------- fused GEMM: t = dinv * ([y|xa] @ Wcat^T + b0 + deg*b1) -----------------
// Block: 128 rows x 128 cols, K=256 in 4 chunks of 64. 4 waves, each 32 rows x 128 cols.
__global__ __launch_bounds__(256) void k_gemm(const f16* __restrict__ A, const f16* __restrict__ Wc,
                                              const float* __restrict__ b0, const float* __restrict__ b1,
                                              const float* __restrict__ dinv, const float* __restrict__ degf,
                                              float* __restrict__ out) {
  __shared__ __align__(16) f16 As[128 * 72];  // stride 72 halves = 144B (pad kills frag-read conflicts)
  __shared__ __align__(16) f16 Bs[128 * 72];
  int tid = threadIdx.x;
  int w = tid >> 6, lane = tid & 63;
  int quad = lane >> 4, l16 = lane & 15;
  int row0 = blockIdx.x * 128;
  f32x4 acc[2][8] = {};

  for (int kc = 0; kc < 4; ++kc) {
#pragma unroll
    for (int jj = 0; jj < 4; ++jj) {
      int q = jj * 256 + tid;  // 1024 chunks of 16B: r = q>>3 (row), c = q&7 (16B chunk)
      int r = q >> 3, c = q & 7;
      *(uint4*)&As[r * 72 + c * 8] = *(const uint4*)&A[(size_t)(row0 + r) * 256 + kc * 64 + c * 8];
      *(uint4*)&Bs[r * 72 + c * 8] = *(const uint4*)&Wc[(size_t)r * 256 + kc * 64 + c * 8];
    }
    __syncthreads();
#pragma unroll
    for (int ks = 0; ks < 2; ++ks) {
      int ko = ks * 32 + quad * 8;
      f16x8 af[2];
#pragma unroll
      for (int mi = 0; mi < 2; ++mi)
        af[mi] = *(const f16x8*)&As[(w * 32 + mi * 16 + l16) * 72 + ko];
#pragma unroll
      for (int ni = 0; ni < 8; ++ni) {
        f16x8 bf = *(const f16x8*)&Bs[(ni * 16 + l16) * 72 + ko];
#pragma unroll
        for (int mi = 0; mi < 2; ++mi)
          acc[mi][ni] = __builtin_amdgcn_mfma_f32_16x16x32_f16(af[mi], bf, acc[mi][ni], 0, 0, 0);
      }
    }
    __syncthreads();
  }
  // epilogue: C/D layout col = lane&15, row = quad*4 + reg
#pragma unroll
  for (int mi = 0; mi < 2; ++mi) {
#pragma unroll
    for (int reg = 0; reg < 4; ++reg) {
      int v = row0 + w * 32 + mi * 16 + quad * 4 + reg;
      if (v < V_N) {
        float dv = dinv[v], gf = degf[v];
#pragma unroll
        for (int ni = 0; ni < 8; ++ni) {
          int c = ni * 16 + l16;
          out[(size_t)v * 128 + c] = dv * (acc[mi][ni][reg] + b0[c] + gf * b1[c]);
        }
      }
    }
  }
}

// ----------------- BN stats over rows -----------------
__global__ __launch_bounds__(256) void k_stats(const float* __restrict__ t, float* __restrict__ stats) {
  __shared__ float red[512];
  int tid = threadIdx.x;
  int c = tid & 127, half = tid >> 7;
  float s = 0.f, sq = 0.f;
  for (int v = blockIdx.x * 2 + half; v < V_N; v += 512) {
    float val = t[(size_t)v * D_N + c];
    s += val;
    sq += val * val;
  }
  red[tid] = s;
  red[256 + tid] = sq;
  __syncthreads();
  if (half == 0) {
    atomicAdd(&stats[c], red[c] + red[128 + c]);
    atomicAdd(&stats[128 + c], red[256 + c] + red[256 + 128 + c]);
  }
}

__global__ void k_finalize(const float* __restrict__ stats, const float* __restrict__ gamma,
                           const float* __restrict__ beta, float* __restrict__ scale,
                           float* __restrict__ shift) {
  int d = threadIdx.x;
  float mu = stats[d] * (1.0f / V_N);
  float var = stats[128 + d] * (1.0f / V_N) - mu * mu;
  float g = gamma[d];
  float sc = g * rsqrtf(var + EPSV);
  scale[d] = sc;
  shift[d] = beta[d] - mu * sc;
}

// ----------------- final: out = relu(scale*t + shift + features) -----------------
__global__ __launch_bounds__(256) void k_final(const float* __restrict__ t, const float* __restrict__ feat,
                                               const float* __restrict__ scale, const float* __restrict__ shift,
                                               float* __restrict__ out) {
  int q = blockIdx.x * blockDim.x + threadIdx.x;  // float4 index
  if (q >= V_N * D_N / 4) return;
  int c4 = q & 31;
  float4 tv = ((const float4*)t)[q];
  float4 fv = ((const float4*)feat)[q];
  float4 sc = ((const float4*)scale)[c4];
  float4 sf = ((const float4*)shift)[c4];
  float4 o;
  o.x = fmaxf(sc.x * tv.x + sf.x + fv.x, 0.f);
  o.y = fmaxf(sc.y * tv.y + sf.y + fv.y, 0.f);
  o.z = fmaxf(sc.z * tv.z + sf.z + fv.z, 0.f);
  o.w = fmaxf(sc.w * tv.w + sf.w + fv.w, 0.f);
  ((float4*)out)[q] = o;
}

extern "C" void kernel_launch(void* const* d_in, const int* in_sizes, int n_in,
                              void* d_out, int out_size, void* d_ws, size_t ws_size,
                              hipStream_t stream) {
  const float* features = (const float*)d_in[0];
  const int* edges = (const int*)d_in[1];
  const float* W0 = (const float*)d_in[2];
  const float* b0 = (const float*)d_in[3];
  const float* W1 = (const float*)d_in[4];
  const float* b1 = (const float*)d_in[5];
  const float* gamma = (const float*)d_in[6];
  const float* beta = (const float*)d_in[7];
  float* out = (float*)d_out;

  char* ws = (char*)d_ws;
  size_t off = 0;
  auto alloc = [&](size_t bytes) -> void* {
    void* p = ws + off;
    off = (off + bytes + 255) & ~(size_t)255;
    return p;
  };
  int* deg = (int*)alloc((size_t)V_N * 4);
  int* csr_off = (int*)alloc((size_t)(V_N + 1) * 4);
  int* adj = (int*)alloc((size_t)2 * E_N * 4);
  float* dinv = (float*)alloc((size_t)V_N * 4);
  float* degf = (float*)alloc((size_t)V_N * 4);
  int* csum = (int*)alloc(512 * 4);
  int* coff = (int*)alloc(512 * 4);
  float* stats = (float*)alloc(256 * 4);
  float* scale = (float*)alloc(128 * 4);
  float* shift = (float*)alloc(128 * 4);
  f16* ycat = (f16*)alloc((size_t)MPAD * 256 * 2);
  f16* Wcat = (f16*)alloc((size_t)3 * 128 * 256 * 2);

  // CSR + dinv/degf
  hipMemsetAsync(deg, 0, (size_t)V_N * 4, stream);
  k_count<<<(2 * E_N + 255) / 256, 256, 0, stream>>>(edges, deg);
  k_chunksum<<<NCHUNK, 256, 0, stream>>>(deg, csum);
  k_scanchunks<<<1, 512, 0, stream>>>(csum, coff);
  k_writeoff<<<NCHUNK, 256, 0, stream>>>(deg, coff, csr_off, dinv, degf);
  hipMemsetAsync(deg, 0, (size_t)V_N * 4, stream);
  k_fill<<<(E_N + 255) / 256, 256, 0, stream>>>(edges, csr_off, deg, adj);
  k_prepw<<<384, 256, 0, stream>>>(W0, W1, Wcat);

  const float* x = features;
  for (int l = 0; l < 3; ++l) {
    k_act<<<(V_N * 32 + 255) / 256, 256, 0, stream>>>(x, scale, shift, l > 0 ? 1 : 0, ycat);
    k_gather<<<V_N / 4, 256, 0, stream>>>(ycat, csr_off, adj);
    k_gemm<<<MPAD / 128, 256, 0, stream>>>(ycat, Wcat + (size_t)l * 128 * 256, b0 + l * D_N, b1 + l * D_N,
                                           dinv, degf, out);
    hipMemsetAsync(stats, 0, 256 * 4, stream);
    k_stats<<<256, 256, 0, stream>>>(out, stats);
    k_finalize<<<1, 128, 0, stream>>>(stats, gamma + l * D_N, beta + l * D_N, scale, shift);
    x = out;
  }
  k_final<<<(V_N * D_N / 4 + 255) / 256, 256, 0, stream>>>(out, features, scale, shift, out);
}

// Round 3
// 480.695 us; speedup vs baseline: 3.8167x; 1.3335x over previous
//
#include <hip/hip_runtime.h>
#include <math.h>
#include <stdint.h>

#define V_N 100000
#define E_N 300000
#define D_N 128
#define EPSV 1e-5f
#define NCHUNK 391   // ceil(V_N/256)
#define MPAD 100096  // 782 * 128

typedef _Float16 f16;
typedef f16 f16x8 __attribute__((ext_vector_type(8)));
typedef f16 f16x4 __attribute__((ext_vector_type(4)));
typedef f16 f16x2 __attribute__((ext_vector_type(2)));
typedef float f32x4 __attribute__((ext_vector_type(4)));

// ----------------- CSR build -----------------
__global__ __launch_bounds__(256) void k_count(const int* __restrict__ edges, int* __restrict__ deg) {
  int i = blockIdx.x * blockDim.x + threadIdx.x;
  if (i < 2 * E_N) atomicAdd(&deg[edges[i]], 1);
}

__global__ __launch_bounds__(256) void k_chunksum(const int* __restrict__ deg, int* __restrict__ csum) {
  __shared__ int red[256];
  int c = blockIdx.x, t = threadIdx.x;
  int i = c * 256 + t;
  red[t] = (i < V_N) ? deg[i] : 0;
  __syncthreads();
  for (int s = 128; s > 0; s >>= 1) {
    if (t < s) red[t] += red[t + s];
    __syncthreads();
  }
  if (t == 0) csum[c] = red[0];
}

__global__ __launch_bounds__(512) void k_scanchunks(const int* __restrict__ csum, int* __restrict__ coff) {
  __shared__ int sh[512];
  int t = threadIdx.x;
  int v = (t < NCHUNK) ? csum[t] : 0;
  sh[t] = v;
  __syncthreads();
  for (int s = 1; s < 512; s <<= 1) {
    int x = (t >= s) ? sh[t - s] : 0;
    __syncthreads();
    sh[t] += x;
    __syncthreads();
  }
  if (t < NCHUNK) coff[t] = sh[t] - v;  // exclusive
}

__global__ __launch_bounds__(256) void k_writeoff(const int* __restrict__ deg, const int* __restrict__ coff,
                                                  int* __restrict__ csr_off, float* __restrict__ dinv,
                                                  float* __restrict__ degf) {
  __shared__ int sh[256];
  int c = blockIdx.x, t = threadIdx.x;
  int i = c * 256 + t;
  int v = (i < V_N) ? deg[i] : 0;
  sh[t] = v;
  __syncthreads();
  for (int s = 1; s < 256; s <<= 1) {
    int x = (t >= s) ? sh[t - s] : 0;
    __syncthreads();
    sh[t] += x;
    __syncthreads();
  }
  int excl = sh[t] - v;
  if (i <= V_N) csr_off[i] = coff[c] + excl;
  if (i < V_N) {
    dinv[i] = 1.0f / (1.0f + (float)v);
    degf[i] = (float)v;
  }
}

__global__ __launch_bounds__(256) void k_fill(const int* __restrict__ edges, const int* __restrict__ csr_off,
                                              int* __restrict__ cursor, int* __restrict__ adj) {
  int e = blockIdx.x * blockDim.x + threadIdx.x;
  if (e >= E_N) return;
  int s = edges[2 * e], d = edges[2 * e + 1];
  int p = atomicAdd(&cursor[s], 1);
  adj[csr_off[s] + p] = d;
  int q = atomicAdd(&cursor[d], 1);
  adj[csr_off[d] + q] = s;
}

// ----------------- weight prep: Wcat[l][n][k] half, k = [W0 row | W1 row] -----------------
__global__ __launch_bounds__(256) void k_prepw(const float* __restrict__ W0, const float* __restrict__ W1,
                                               f16* __restrict__ Wc) {
  int idx = blockIdx.x * 256 + threadIdx.x;
  if (idx >= 3 * 128 * 256) return;
  int l = idx >> 15;
  int rem = idx & 32767;
  int n = rem >> 8, k = rem & 255;
  float v = (k < 128) ? W0[l * 16384 + n * 128 + k] : W1[l * 16384 + n * 128 + (k - 128)];
  Wc[idx] = (f16)v;
}

// ----------------- activation: ycat[v][0:128] = f16(act(x[v])); block 0 zeroes stats ------
__global__ __launch_bounds__(256) void k_act(const float* __restrict__ x, const float* __restrict__ scale,
                                             const float* __restrict__ shift, int aff, f16* __restrict__ ycat,
                                             float* __restrict__ stats) {
  if (blockIdx.x == 0) stats[threadIdx.x] = 0.f;  // 256 floats, exactly one block's worth
  int q = blockIdx.x * 256 + threadIdx.x;  // float4 index over V_N*128
  if (q >= V_N * 32) return;
  int v = q >> 5, c4 = q & 31;
  float4 xv = ((const float4*)x)[q];
  if (aff) {
    float4 sc = ((const float4*)scale)[c4];
    float4 sf = ((const float4*)shift)[c4];
    xv.x = fmaxf(sc.x * xv.x + sf.x, 0.f);
    xv.y = fmaxf(sc.y * xv.y + sf.y, 0.f);
    xv.z = fmaxf(sc.z * xv.z + sf.z, 0.f);
    xv.w = fmaxf(sc.w * xv.w + sf.w, 0.f);
  }
  f16x4 h;
  h[0] = (f16)xv.x; h[1] = (f16)xv.y; h[2] = (f16)xv.z; h[3] = (f16)xv.w;
  *(f16x4*)&ycat[(size_t)v * 256 + c4 * 4] = h;
}

// ----------------- gather: ycat[v][128:256] = f16(sum_{u in N(v)} ycat[u][0:128]) ---------
// One wave per vertex. Batch-8 clamped loads for ILP (deg >= 2 guaranteed by ring edges).
__global__ __launch_bounds__(256) void k_gather(f16* __restrict__ ycat, const int* __restrict__ csr_off,
                                                const int* __restrict__ adj) {
  int w = threadIdx.x >> 6, lane = threadIdx.x & 63;
  int v = blockIdx.x * 4 + w;
  if (v >= V_N) return;
  int s = csr_off[v], e = csr_off[v + 1];
  float a0[4] = {0.f, 0.f, 0.f, 0.f}, a1[4] = {0.f, 0.f, 0.f, 0.f};
  for (int p = s; p < e; p += 8) {
    int idx[8];
#pragma unroll
    for (int j = 0; j < 8; ++j) {
      int pp = p + j;
      idx[j] = adj[pp < e ? pp : e - 1];
    }
    f16x2 h[8];
#pragma unroll
    for (int j = 0; j < 8; ++j) h[j] = *(const f16x2*)&ycat[(size_t)idx[j] * 256 + lane * 2];
#pragma unroll
    for (int j = 0; j < 8; ++j) {
      if (p + j < e) {  // wave-uniform condition
        a0[j & 3] += (float)h[j][0];
        a1[j & 3] += (float)h[j][1];
      }
    }
  }
  float s0 = (a0[0] + a0[1]) + (a0[2] + a0[3]);
  float s1 = (a1[0] + a1[1]) + (a1[2] + a1[3]);
  f16x2 o;
  o[0] = (f16)s0;
  o[1] = (f16)s1;
  *(f16x2*)&ycat[(size_t)v * 256 + 128 + lane * 2] = o;
}

// ----------------- fused GEMM: t = dinv * ([y|xa] @ Wcat^T + b0 + deg*b1); + BN stats -----
// Block: 128 rows x 128 cols, K=256 in 4 chunks of 64. 4 waves, each 32 rows x 128 cols.
__global__ __launch_bounds__(256) void k_gemm(const f16* __restrict__ A, const f16* __restrict__ Wc,
                                              const float* __restrict__ b0, const float* __restrict__ b1,
                                              const float* __restrict__ dinv, const float* __restrict__ degf,
                                              float* __restrict__ out, float* __restrict__ stats) {
  __shared__ __align__(16) f16 As[128 * 72];  // stride 72 halves = 144B (pad kills frag-read conflicts)
  __shared__ __align__(16) f16 Bs[128 * 72];
  __shared__ float sstat[256];
  int tid = threadIdx.x;
  int w = tid >> 6, lane = tid & 63;
  int quad = lane >> 4, l16 = lane & 15;
  int row0 = blockIdx.x * 128;
  f32x4 acc[2][8] = {};

  for (int kc = 0; kc < 4; ++kc) {
#pragma unroll
    for (int jj = 0; jj < 4; ++jj) {
      int q = jj * 256 + tid;  // 1024 chunks of 16B: r = q>>3 (row), c = q&7 (16B chunk)
      int r = q >> 3, c = q & 7;
      *(uint4*)&As[r * 72 + c * 8] = *(const uint4*)&A[(size_t)(row0 + r) * 256 + kc * 64 + c * 8];
      *(uint4*)&Bs[r * 72 + c * 8] = *(const uint4*)&Wc[(size_t)r * 256 + kc * 64 + c * 8];
    }
    __syncthreads();
#pragma unroll
    for (int ks = 0; ks < 2; ++ks) {
      int ko = ks * 32 + quad * 8;
      f16x8 af[2];
#pragma unroll
      for (int mi = 0; mi < 2; ++mi)
        af[mi] = *(const f16x8*)&As[(w * 32 + mi * 16 + l16) * 72 + ko];
#pragma unroll
      for (int ni = 0; ni < 8; ++ni) {
        f16x8 bf = *(const f16x8*)&Bs[(ni * 16 + l16) * 72 + ko];
#pragma unroll
        for (int mi = 0; mi < 2; ++mi)
          acc[mi][ni] = __builtin_amdgcn_mfma_f32_16x16x32_f16(af[mi], bf, acc[mi][ni], 0, 0, 0);
      }
    }
    __syncthreads();
  }

  // epilogue: C/D layout col = l16, row = quad*4 + reg. Also accumulate BN stats.
  sstat[tid] = 0.f;
  float csum[8] = {}, csq[8] = {};
#pragma unroll
  for (int mi = 0; mi < 2; ++mi) {
#pragma unroll
    for (int reg = 0; reg < 4; ++reg) {
      int v = row0 + w * 32 + mi * 16 + quad * 4 + reg;
      if (v < V_N) {
        float dv = dinv[v], gf = degf[v];
#pragma unroll
        for (int ni = 0; ni < 8; ++ni) {
          int c = ni * 16 + l16;
          float t = dv * (acc[mi][ni][reg] + b0[c] + gf * b1[c]);
          out[(size_t)v * 128 + c] = t;
          csum[ni] += t;
          csq[ni] += t * t;
        }
      }
    }
  }
  // reduce across the 4 quads (same col set): xor over lane bits 4,5
#pragma unroll
  for (int ni = 0; ni < 8; ++ni) {
    csum[ni] += __shfl_xor(csum[ni], 16);
    csum[ni] += __shfl_xor(csum[ni], 32);
    csq[ni] += __shfl_xor(csq[ni], 16);
    csq[ni] += __shfl_xor(csq[ni], 32);
  }
  __syncthreads();
  if (quad == 0) {
#pragma unroll
    for (int ni = 0; ni < 8; ++ni) {
      int c = ni * 16 + l16;
      atomicAdd(&sstat[c], csum[ni]);
      atomicAdd(&sstat[128 + c], csq[ni]);
    }
  }
  __syncthreads();
  if (tid < 128) {
    atomicAdd(&stats[tid], sstat[tid]);
    atomicAdd(&stats[128 + tid], sstat[128 + tid]);
  }
}

__global__ void k_finalize(const float* __restrict__ stats, const float* __restrict__ gamma,
                           const float* __restrict__ beta, float* __restrict__ scale,
                           float* __restrict__ shift) {
  int d = threadIdx.x;
  float mu = stats[d] * (1.0f / V_N);
  float var = stats[128 + d] * (1.0f / V_N) - mu * mu;
  float g = gamma[d];
  float sc = g * rsqrtf(var + EPSV);
  scale[d] = sc;
  shift[d] = beta[d] - mu * sc;
}

// ----------------- final: out = relu(scale*t + shift + features) -----------------
__global__ __launch_bounds__(256) void k_final(const float* __restrict__ t, const float* __restrict__ feat,
                                               const float* __restrict__ scale, const float* __restrict__ shift,
                                               float* __restrict__ out) {
  int q = blockIdx.x * blockDim.x + threadIdx.x;  // float4 index
  if (q >= V_N * D_N / 4) return;
  int c4 = q & 31;
  float4 tv = ((const float4*)t)[q];
  float4 fv = ((const float4*)feat)[q];
  float4 sc = ((const float4*)scale)[c4];
  float4 sf = ((const float4*)shift)[c4];
  float4 o;
  o.x = fmaxf(sc.x * tv.x + sf.x + fv.x, 0.f);
  o.y = fmaxf(sc.y * tv.y + sf.y + fv.y, 0.f);
  o.z = fmaxf(sc.z * tv.z + sf.z + fv.z, 0.f);
  o.w = fmaxf(sc.w * tv.w + sf.w + fv.w, 0.f);
  ((float4*)out)[q] = o;
}

extern "C" void kernel_launch(void* const* d_in, const int* in_sizes, int n_in,
                              void* d_out, int out_size, void* d_ws, size_t ws_size,
                              hipStream_t stream) {
  const float* features = (const float*)d_in[0];
  const int* edges = (const int*)d_in[1];
  const float* W0 = (const float*)d_in[2];
  const float* b0 = (const float*)d_in[3];
  const float* W1 = (const float*)d_in[4];
  const float* b1 = (const float*)d_in[5];
  const float* gamma = (const float*)d_in[6];
  const float* beta = (const float*)d_in[7];
  float* out = (float*)d_out;

  char* ws = (char*)d_ws;
  size_t off = 0;
  auto alloc = [&](size_t bytes) -> void* {
    void* p = ws + off;
    off = (off + bytes + 255) & ~(size_t)255;
    return p;
  };
  int* deg = (int*)alloc((size_t)V_N * 4);
  int* csr_off = (int*)alloc((size_t)(V_N + 1) * 4);
  int* adj = (int*)alloc((size_t)2 * E_N * 4);
  float* dinv = (float*)alloc((size_t)V_N * 4);
  float* degf = (float*)alloc((size_t)V_N * 4);
  int* csum = (int*)alloc(512 * 4);
  int* coff = (int*)alloc(512 * 4);
  float* stats = (float*)alloc(256 * 4);
  float* scale = (float*)alloc(128 * 4);
  float* shift = (float*)alloc(128 * 4);
  f16* ycat = (f16*)alloc((size_t)MPAD * 256 * 2);
  f16* Wcat = (f16*)alloc((size_t)3 * 128 * 256 * 2);

  // CSR + dinv/degf
  hipMemsetAsync(deg, 0, (size_t)V_N * 4, stream);
  k_count<<<(2 * E_N + 255) / 256, 256, 0, stream>>>(edges, deg);
  k_chunksum<<<NCHUNK, 256, 0, stream>>>(deg, csum);
  k_scanchunks<<<1, 512, 0, stream>>>(csum, coff);
  k_writeoff<<<NCHUNK, 256, 0, stream>>>(deg, coff, csr_off, dinv, degf);
  hipMemsetAsync(deg, 0, (size_t)V_N * 4, stream);
  k_fill<<<(E_N + 255) / 256, 256, 0, stream>>>(edges, csr_off, deg, adj);
  k_prepw<<<384, 256, 0, stream>>>(W0, W1, Wcat);

  const float* x = features;
  for (int l = 0; l < 3; ++l) {
    k_act<<<(V_N * 32 + 255) / 256, 256, 0, stream>>>(x, scale, shift, l > 0 ? 1 : 0, ycat, stats);
    k_gather<<<V_N / 4, 256, 0, stream>>>(ycat, csr_off, adj);
    k_gemm<<<MPAD / 128, 256, 0, stream>>>(ycat, Wcat + (size_t)l * 128 * 256, b0 + l * D_N, b1 + l * D_N,
                                           dinv, degf, out, stats);
    k_finalize<<<1, 128, 0, stream>>>(stats, gamma + l * D_N, beta + l * D_N, scale, shift);
    x = out;
  }
  k_final<<<(V_N * D_N / 4 + 255) / 256, 256, 0, stream>>>(out, features, scale, shift, out);
}

// Round 4
// 397.836 us; speedup vs baseline: 4.6116x; 1.2083x over previous
//
#include <hip/hip_runtime.h>
#include <math.h>
#include <stdint.h>

#define V_N 100000
#define E_N 300000
#define D_N 128
#define EPSV 1e-5f
#define NCHUNK 391   // ceil(V_N/256)
#define MPAD 100096  // 1564 * 64

typedef _Float16 f16;
typedef f16 f16x8 __attribute__((ext_vector_type(8)));
typedef f16 f16x4 __attribute__((ext_vector_type(4)));
typedef f16 f16x2 __attribute__((ext_vector_type(2)));
typedef float f32x4 __attribute__((ext_vector_type(4)));

// async global->LDS, 16B per lane; lds base must be wave-uniform
#define GLD(g, l) __builtin_amdgcn_global_load_lds( \
    (__attribute__((address_space(1))) void*)(g),   \
    (__attribute__((address_space(3))) void*)(l), 16, 0, 0)

// ----------------- CSR build -----------------
__global__ __launch_bounds__(256) void k_count(const int* __restrict__ edges, int* __restrict__ deg) {
  int i = blockIdx.x * blockDim.x + threadIdx.x;
  if (i < 2 * E_N) atomicAdd(&deg[edges[i]], 1);
}

__global__ __launch_bounds__(256) void k_chunksum(const int* __restrict__ deg, int* __restrict__ csum) {
  __shared__ int red[256];
  int c = blockIdx.x, t = threadIdx.x;
  int i = c * 256 + t;
  red[t] = (i < V_N) ? deg[i] : 0;
  __syncthreads();
  for (int s = 128; s > 0; s >>= 1) {
    if (t < s) red[t] += red[t + s];
    __syncthreads();
  }
  if (t == 0) csum[c] = red[0];
}

__global__ __launch_bounds__(512) void k_scanchunks(const int* __restrict__ csum, int* __restrict__ coff) {
  __shared__ int sh[512];
  int t = threadIdx.x;
  int v = (t < NCHUNK) ? csum[t] : 0;
  sh[t] = v;
  __syncthreads();
  for (int s = 1; s < 512; s <<= 1) {
    int x = (t >= s) ? sh[t - s] : 0;
    __syncthreads();
    sh[t] += x;
    __syncthreads();
  }
  if (t < NCHUNK) coff[t] = sh[t] - v;  // exclusive
}

__global__ __launch_bounds__(256) void k_writeoff(const int* __restrict__ deg, const int* __restrict__ coff,
                                                  int* __restrict__ csr_off, float* __restrict__ dinv,
                                                  float* __restrict__ degf) {
  __shared__ int sh[256];
  int c = blockIdx.x, t = threadIdx.x;
  int i = c * 256 + t;
  int v = (i < V_N) ? deg[i] : 0;
  sh[t] = v;
  __syncthreads();
  for (int s = 1; s < 256; s <<= 1) {
    int x = (t >= s) ? sh[t - s] : 0;
    __syncthreads();
    sh[t] += x;
    __syncthreads();
  }
  int excl = sh[t] - v;
  if (i <= V_N) csr_off[i] = coff[c] + excl;
  if (i < V_N) {
    dinv[i] = 1.0f / (1.0f + (float)v);
    degf[i] = (float)v;
  }
}

__global__ __launch_bounds__(256) void k_fill(const int* __restrict__ edges, const int* __restrict__ csr_off,
                                              int* __restrict__ cursor, int* __restrict__ adj) {
  int e = blockIdx.x * blockDim.x + threadIdx.x;
  if (e >= E_N) return;
  int s = edges[2 * e], d = edges[2 * e + 1];
  int p = atomicAdd(&cursor[s], 1);
  adj[csr_off[s] + p] = d;
  int q = atomicAdd(&cursor[d], 1);
  adj[csr_off[d] + q] = s;
}

// ----------------- weight prep: Wcat[l][n][k] half, k = [W0 row | W1 row] -----------------
__global__ __launch_bounds__(256) void k_prepw(const float* __restrict__ W0, const float* __restrict__ W1,
                                               f16* __restrict__ Wc) {
  int idx = blockIdx.x * 256 + threadIdx.x;
  if (idx >= 3 * 128 * 256) return;
  int l = idx >> 15;
  int rem = idx & 32767;
  int n = rem >> 8, k = rem & 255;
  float v = (k < 128) ? W0[l * 16384 + n * 128 + k] : W1[l * 16384 + n * 128 + (k - 128)];
  Wc[idx] = (f16)v;
}

// ----------------- cast: y[v] = f16(features[v]) (layer 0 input) -----------------
__global__ __launch_bounds__(256) void k_cast(const float* __restrict__ x, f16* __restrict__ y) {
  int q = blockIdx.x * 256 + threadIdx.x;  // float4 index over V_N*128
  if (q >= V_N * 32) return;
  float4 xv = ((const float4*)x)[q];
  f16x4 h;
  h[0] = (f16)xv.x; h[1] = (f16)xv.y; h[2] = (f16)xv.z; h[3] = (f16)xv.w;
  *(f16x4*)&y[(size_t)q * 4] = h;
}

// ----------------- gather -----------------
// MODE 0: neighbors from y (raw), write xa only.
// MODE 1: neighbors from t with relu(scale*t+shift) on the fly; also write y_v.
// Blocks 0..63 zero the 64 stats shards.
template <int MODE>
__global__ __launch_bounds__(256) void k_gather(const f16* __restrict__ tin, f16* __restrict__ y,
                                                f16* __restrict__ xa, const int* __restrict__ csr_off,
                                                const int* __restrict__ adj, const float* __restrict__ scale,
                                                const float* __restrict__ shift, float* __restrict__ stats) {
  if (blockIdx.x < 64) stats[blockIdx.x * 256 + threadIdx.x] = 0.f;
  int w = threadIdx.x >> 6, lane = threadIdx.x & 63;
  int v = blockIdx.x * 4 + w;
  if (v >= V_N) return;
  int c0 = lane * 2;
  float sc0 = 1.f, sf0 = 0.f, sc1 = 1.f, sf1 = 0.f;
  if (MODE) { sc0 = scale[c0]; sf0 = shift[c0]; sc1 = scale[c0 + 1]; sf1 = shift[c0 + 1]; }
  const f16* base = MODE ? tin : y;
  int s = csr_off[v], e = csr_off[v + 1];
  float a0 = 0.f, a1 = 0.f;
  for (int p = s; p < e; p += 8) {
    int idx[8];
#pragma unroll
    for (int j = 0; j < 8; ++j) {
      int pp = p + j;
      idx[j] = adj[pp < e ? pp : e - 1];
    }
    f16x2 h[8];
#pragma unroll
    for (int j = 0; j < 8; ++j) h[j] = *(const f16x2*)&base[(size_t)idx[j] * 128 + c0];
#pragma unroll
    for (int j = 0; j < 8; ++j) {
      if (p + j < e) {  // wave-uniform
        float u0 = (float)h[j][0], u1 = (float)h[j][1];
        if (MODE) {
          u0 = fmaxf(sc0 * u0 + sf0, 0.f);
          u1 = fmaxf(sc1 * u1 + sf1, 0.f);
        }
        a0 += u0; a1 += u1;
      }
    }
  }
  if (MODE) {
    f16x2 tv = *(const f16x2*)&tin[(size_t)v * 128 + c0];
    f16x2 yv;
    yv[0] = (f16)fmaxf(sc0 * (float)tv[0] + sf0, 0.f);
    yv[1] = (f16)fmaxf(sc1 * (float)tv[1] + sf1, 0.f);
    *(f16x2*)&y[(size_t)v * 128 + c0] = yv;
  }
  f16x2 o;
  o[0] = (f16)a0; o[1] = (f16)a1;
  *(f16x2*)&xa[(size_t)v * 128 + c0] = o;
}

// ----------------- fused GEMM: t = dinv * ([y|xa] @ Wcat^T + b0 + deg*b1); + BN stats -----
// 64 rows x 128 cols per block (1564 blocks), K=256 in 4 chunks of 64 halves.
// XOR-swizzled LDS (16B chunks), global_load_lds staging. t written as f16.
__global__ __launch_bounds__(256) void k_gemm(const f16* __restrict__ y, const f16* __restrict__ xa,
                                              const f16* __restrict__ Wc,
                                              const float* __restrict__ b0, const float* __restrict__ b1,
                                              const float* __restrict__ dinv, const float* __restrict__ degf,
                                              f16* __restrict__ tbuf, float* __restrict__ stats) {
  __shared__ __align__(16) f16 As[64 * 64];    // 512 x 16B chunks, chunk (r,c) at slot r*8 + (c^(r&7))
  __shared__ __align__(16) f16 Bs[128 * 64];   // 1024 x 16B chunks
  __shared__ float sstat[256];
  int tid = threadIdx.x;
  int w = tid >> 6, lane = tid & 63;
  int quad = lane >> 4, l16 = lane & 15;
  int row0 = blockIdx.x * 64;
  f32x4 acc[8] = {};

  for (int kc = 0; kc < 4; ++kc) {
    const f16* Abase = (kc < 2) ? y : xa;
    int koff = (kc & 1) * 64;
    // stage A: 512 chunks, 2 wave-instructions per wave
#pragma unroll
    for (int i = 0; i < 2; ++i) {
      int s = (w * 2 + i) * 64 + lane;
      int r = s >> 3, c = (s & 7) ^ (r & 7);
      GLD(Abase + (size_t)(row0 + r) * 128 + koff + c * 8, &As[(w * 2 + i) * 512]);
    }
    // stage B: 1024 chunks, 4 per wave
#pragma unroll
    for (int i = 0; i < 4; ++i) {
      int s = (w * 4 + i) * 64 + lane;
      int r = s >> 3, c = (s & 7) ^ (r & 7);
      GLD(Wc + (size_t)r * 256 + kc * 64 + c * 8, &Bs[(w * 4 + i) * 512]);
    }
    __syncthreads();  // drains vmcnt (global_load_lds) + barrier
#pragma unroll
    for (int ks = 0; ks < 2; ++ks) {
      int cc = ks * 4 + quad;
      int rr = w * 16 + l16;
      f16x8 af = *(const f16x8*)&As[(rr * 8 + (cc ^ (rr & 7))) * 8];
#pragma unroll
      for (int ni = 0; ni < 8; ++ni) {
        int rb = ni * 16 + l16;
        f16x8 bf = *(const f16x8*)&Bs[(rb * 8 + (cc ^ (rb & 7))) * 8];
        acc[ni] = __builtin_amdgcn_mfma_f32_16x16x32_f16(af, bf, acc[ni], 0, 0, 0);
      }
    }
    __syncthreads();
  }

  sstat[tid] = 0.f;
  __syncthreads();

  float b0c[8], b1c[8];
#pragma unroll
  for (int ni = 0; ni < 8; ++ni) {
    b0c[ni] = b0[ni * 16 + l16];
    b1c[ni] = b1[ni * 16 + l16];
  }
  float csum[8] = {}, csq[8] = {};
  // C/D layout: col = l16, row = quad*4 + reg
#pragma unroll
  for (int reg = 0; reg < 4; ++reg) {
    int v = row0 + w * 16 + quad * 4 + reg;
    if (v < V_N) {
      float dv = dinv[v], gf = degf[v];
#pragma unroll
      for (int ni = 0; ni < 8; ++ni) {
        float tv = dv * (acc[ni][reg] + b0c[ni] + gf * b1c[ni]);
        tbuf[(size_t)v * 128 + ni * 16 + l16] = (f16)tv;
        csum[ni] += tv;
        csq[ni] += tv * tv;
      }
    }
  }
#pragma unroll
  for (int ni = 0; ni < 8; ++ni) {
    csum[ni] += __shfl_xor(csum[ni], 16);
    csum[ni] += __shfl_xor(csum[ni], 32);
    csq[ni] += __shfl_xor(csq[ni], 16);
    csq[ni] += __shfl_xor(csq[ni], 32);
  }
  if (quad == 0) {
#pragma unroll
    for (int ni = 0; ni < 8; ++ni) {
      atomicAdd(&sstat[ni * 16 + l16], csum[ni]);
      atomicAdd(&sstat[128 + ni * 16 + l16], csq[ni]);
    }
  }
  __syncthreads();
  atomicAdd(&stats[(blockIdx.x & 63) * 256 + tid], sstat[tid]);  // 64-way sharded
}

__global__ void k_finalize(const float* __restrict__ stats, const float* __restrict__ gamma,
                           const float* __restrict__ beta, float* __restrict__ scale,
                           float* __restrict__ shift) {
  int d = threadIdx.x;  // 128
  float s = 0.f, sq = 0.f;
#pragma unroll 8
  for (int h = 0; h < 64; ++h) {
    s += stats[h * 256 + d];
    sq += stats[h * 256 + 128 + d];
  }
  float mu = s * (1.0f / V_N);
  float var = sq * (1.0f / V_N) - mu * mu;
  float scv = gamma[d] * rsqrtf(var + EPSV);
  scale[d] = scv;
  shift[d] = beta[d] - mu * scv;
}

// ----------------- final: out = relu(scale*t + shift + features) -----------------
__global__ __launch_bounds__(256) void k_final(const f16* __restrict__ t, const float* __restrict__ feat,
                                               const float* __restrict__ scale, const float* __restrict__ shift,
                                               float* __restrict__ out) {
  int q = blockIdx.x * 256 + threadIdx.x;  // float4 index
  if (q >= V_N * 32) return;
  int c4 = q & 31;
  f16x4 tv = *(const f16x4*)&t[(size_t)q * 4];
  float4 fv = ((const float4*)feat)[q];
  float4 sc = ((const float4*)scale)[c4];
  float4 sf = ((const float4*)shift)[c4];
  float4 o;
  o.x = fmaxf(sc.x * (float)tv[0] + sf.x + fv.x, 0.f);
  o.y = fmaxf(sc.y * (float)tv[1] + sf.y + fv.y, 0.f);
  o.z = fmaxf(sc.z * (float)tv[2] + sf.z + fv.z, 0.f);
  o.w = fmaxf(sc.w * (float)tv[3] + sf.w + fv.w, 0.f);
  ((float4*)out)[q] = o;
}

extern "C" void kernel_launch(void* const* d_in, const int* in_sizes, int n_in,
                              void* d_out, int out_size, void* d_ws, size_t ws_size,
                              hipStream_t stream) {
  const float* features = (const float*)d_in[0];
  const int* edges = (const int*)d_in[1];
  const float* W0 = (const float*)d_in[2];
  const float* b0 = (const float*)d_in[3];
  const float* W1 = (const float*)d_in[4];
  const float* b1 = (const float*)d_in[5];
  const float* gamma = (const float*)d_in[6];
  const float* beta = (const float*)d_in[7];
  float* out = (float*)d_out;

  char* ws = (char*)d_ws;
  size_t off = 0;
  auto alloc = [&](size_t bytes) -> void* {
    void* p = ws + off;
    off = (off + bytes + 255) & ~(size_t)255;
    return p;
  };
  int* deg = (int*)alloc((size_t)V_N * 4);
  int* csr_off = (int*)alloc((size_t)(V_N + 1) * 4);
  int* adj = (int*)alloc((size_t)2 * E_N * 4);
  float* dinv = (float*)alloc((size_t)V_N * 4);
  float* degf = (float*)alloc((size_t)V_N * 4);
  int* csum = (int*)alloc(512 * 4);
  int* coff = (int*)alloc(512 * 4);
  float* stats = (float*)alloc(64 * 256 * 4);
  float* scale = (float*)alloc(128 * 4);
  float* shift = (float*)alloc(128 * 4);
  f16* y = (f16*)alloc((size_t)MPAD * 128 * 2);
  f16* xa = (f16*)alloc((size_t)MPAD * 128 * 2);
  f16* tbuf = (f16*)alloc((size_t)MPAD * 128 * 2);
  f16* Wcat = (f16*)alloc((size_t)3 * 128 * 256 * 2);

  // CSR + dinv/degf
  hipMemsetAsync(deg, 0, (size_t)V_N * 4, stream);
  k_count<<<(2 * E_N + 255) / 256, 256, 0, stream>>>(edges, deg);
  k_chunksum<<<NCHUNK, 256, 0, stream>>>(deg, csum);
  k_scanchunks<<<1, 512, 0, stream>>>(csum, coff);
  k_writeoff<<<NCHUNK, 256, 0, stream>>>(deg, coff, csr_off, dinv, degf);
  hipMemsetAsync(deg, 0, (size_t)V_N * 4, stream);
  k_fill<<<(E_N + 255) / 256, 256, 0, stream>>>(edges, csr_off, deg, adj);
  k_prepw<<<384, 256, 0, stream>>>(W0, W1, Wcat);
  k_cast<<<12500, 256, 0, stream>>>(features, y);

  for (int l = 0; l < 3; ++l) {
    if (l == 0)
      k_gather<0><<<25000, 256, 0, stream>>>(tbuf, y, xa, csr_off, adj, scale, shift, stats);
    else
      k_gather<1><<<25000, 256, 0, stream>>>(tbuf, y, xa, csr_off, adj, scale, shift, stats);
    k_gemm<<<MPAD / 64, 256, 0, stream>>>(y, xa, Wcat + (size_t)l * 128 * 256, b0 + l * D_N,
                                          b1 + l * D_N, dinv, degf, tbuf, stats);
    k_finalize<<<1, 128, 0, stream>>>(stats, gamma + l * D_N, beta + l * D_N, scale, shift);
  }
  k_final<<<12500, 256, 0, stream>>>(tbuf, features, scale, shift, out);
}

// Round 5
// 369.081 us; speedup vs baseline: 4.9709x; 1.0779x over previous
//
#include <hip/hip_runtime.h>
#include <math.h>
#include <stdint.h>

#define V_N 100000
#define E_N 300000
#define D_N 128
#define EPSV 1e-5f
#define NCHUNK 391   // ceil(V_N/256)
#define MPAD 100096  // 1564 * 64

typedef _Float16 f16;
typedef f16 f16x8 __attribute__((ext_vector_type(8)));
typedef f16 f16x4 __attribute__((ext_vector_type(4)));
typedef f16 f16x2 __attribute__((ext_vector_type(2)));
typedef float f32x4 __attribute__((ext_vector_type(4)));

// async global->LDS, 16B per lane; lds base must be wave-uniform
#define GLD(g, l) __builtin_amdgcn_global_load_lds( \
    (__attribute__((address_space(1))) void*)(g),   \
    (__attribute__((address_space(3))) void*)(l), 16, 0, 0)

// ----------------- CSR build -----------------
__global__ __launch_bounds__(256) void k_count(const int* __restrict__ edges, int* __restrict__ deg) {
  int i = blockIdx.x * blockDim.x + threadIdx.x;
  if (i < 2 * E_N) atomicAdd(&deg[edges[i]], 1);
}

__global__ __launch_bounds__(256) void k_chunksum(const int* __restrict__ deg, int* __restrict__ csum) {
  __shared__ int red[256];
  int c = blockIdx.x, t = threadIdx.x;
  int i = c * 256 + t;
  red[t] = (i < V_N) ? deg[i] : 0;
  __syncthreads();
  for (int s = 128; s > 0; s >>= 1) {
    if (t < s) red[t] += red[t + s];
    __syncthreads();
  }
  if (t == 0) csum[c] = red[0];
}

__global__ __launch_bounds__(512) void k_scanchunks(const int* __restrict__ csum, int* __restrict__ coff) {
  __shared__ int sh[512];
  int t = threadIdx.x;
  int v = (t < NCHUNK) ? csum[t] : 0;
  sh[t] = v;
  __syncthreads();
  for (int s = 1; s < 512; s <<= 1) {
    int x = (t >= s) ? sh[t - s] : 0;
    __syncthreads();
    sh[t] += x;
    __syncthreads();
  }
  if (t < NCHUNK) coff[t] = sh[t] - v;  // exclusive
}

__global__ __launch_bounds__(256) void k_writeoff(const int* __restrict__ deg, const int* __restrict__ coff,
                                                  int* __restrict__ csr_off, float* __restrict__ dinv,
                                                  float* __restrict__ degf) {
  __shared__ int sh[256];
  int c = blockIdx.x, t = threadIdx.x;
  int i = c * 256 + t;
  int v = (i < V_N) ? deg[i] : 0;
  sh[t] = v;
  __syncthreads();
  for (int s = 1; s < 256; s <<= 1) {
    int x = (t >= s) ? sh[t - s] : 0;
    __syncthreads();
    sh[t] += x;
    __syncthreads();
  }
  int excl = sh[t] - v;
  if (i <= V_N) csr_off[i] = coff[c] + excl;
  if (i < V_N) {
    dinv[i] = 1.0f / (1.0f + (float)v);
    degf[i] = (float)v;
  }
}

__global__ __launch_bounds__(256) void k_fill(const int* __restrict__ edges, const int* __restrict__ csr_off,
                                              int* __restrict__ cursor, int* __restrict__ adj) {
  int e = blockIdx.x * blockDim.x + threadIdx.x;
  if (e >= E_N) return;
  int s = edges[2 * e], d = edges[2 * e + 1];
  int p = atomicAdd(&cursor[s], 1);
  adj[csr_off[s] + p] = d;
  int q = atomicAdd(&cursor[d], 1);
  adj[csr_off[d] + q] = s;
}

// ----------------- weight prep: Wcat[l][n][k] half, k = [W0 row | W1 row] -----------------
__global__ __launch_bounds__(256) void k_prepw(const float* __restrict__ W0, const float* __restrict__ W1,
                                               f16* __restrict__ Wc) {
  int idx = blockIdx.x * 256 + threadIdx.x;
  if (idx >= 3 * 128 * 256) return;
  int l = idx >> 15;
  int rem = idx & 32767;
  int n = rem >> 8, k = rem & 255;
  float v = (k < 128) ? W0[l * 16384 + n * 128 + k] : W1[l * 16384 + n * 128 + (k - 128)];
  Wc[idx] = (f16)v;
}

// ----------------- cast: y[v] = f16(features[v]) (layer 0 input) -----------------
__global__ __launch_bounds__(256) void k_cast(const float* __restrict__ x, f16* __restrict__ y) {
  int q = blockIdx.x * 256 + threadIdx.x;  // float4 index over V_N*128
  if (q >= V_N * 32) return;
  float4 xv = ((const float4*)x)[q];
  f16x4 h;
  h[0] = (f16)xv.x; h[1] = (f16)xv.y; h[2] = (f16)xv.z; h[3] = (f16)xv.w;
  *(f16x4*)&y[(size_t)q * 4] = h;
}

// ----------------- gather: 4 vertices per wave, batch-8 loads, packed-f16 math ----------
// MODE 0: neighbors from y (raw), write xa only.
// MODE 1: neighbors from t with relu(scale*t+shift) on the fly; also write y_v.
// Blocks 0..63 zero the 64 stats shards. Grid: 6250 blocks x 4 waves x 4 verts = 100000.
template <int MODE>
__global__ __launch_bounds__(256) void k_gather(const f16* __restrict__ tin, f16* __restrict__ y,
                                                f16* __restrict__ xa, const int* __restrict__ csr_off,
                                                const int* __restrict__ adj, const float* __restrict__ scale,
                                                const float* __restrict__ shift, float* __restrict__ stats) {
  if (blockIdx.x < 64) stats[blockIdx.x * 256 + threadIdx.x] = 0.f;
  int w = threadIdx.x >> 6, lane = threadIdx.x & 63;
  int vbase = (blockIdx.x * 4 + w) * 4;
  int c0 = lane * 2;
  f16x2 scv = {}, sfv = {};
  if (MODE) {
    scv[0] = (f16)scale[c0]; scv[1] = (f16)scale[c0 + 1];
    sfv[0] = (f16)shift[c0]; sfv[1] = (f16)shift[c0 + 1];
  }
  const f16* base = MODE ? tin : y;
  int s[4], e[4];
#pragma unroll
  for (int i = 0; i < 4; ++i) {
    s[i] = csr_off[vbase + i];
    e[i] = csr_off[vbase + i + 1];
  }
  // all 32 adjacency indices (clamped), then all 32 row loads -> 32 outstanding VMEM ops
  int idx[4][8];
#pragma unroll
  for (int i = 0; i < 4; ++i)
#pragma unroll
    for (int j = 0; j < 8; ++j) {
      int pp = s[i] + j;
      idx[i][j] = adj[pp < e[i] ? pp : e[i] - 1];
    }
  f16x2 h[4][8];
#pragma unroll
  for (int i = 0; i < 4; ++i)
#pragma unroll
    for (int j = 0; j < 8; ++j)
      h[i][j] = *(const f16x2*)&base[(size_t)idx[i][j] * 128 + c0];
  f16x2 own[4];
  if (MODE) {
#pragma unroll
    for (int i = 0; i < 4; ++i) own[i] = *(const f16x2*)&tin[(size_t)(vbase + i) * 128 + c0];
  }
  f16x2 zero = {};
#pragma unroll
  for (int i = 0; i < 4; ++i) {
    float a0, a1;
    {
#pragma unroll
      for (int j = 0; j < 8; ++j) {
        f16x2 u = h[i][j];
        if (MODE) u = __builtin_elementwise_max(scv * u + sfv, zero);
        h[i][j] = (s[i] + j < e[i]) ? u : zero;
      }
      f16x2 t01 = h[i][0] + h[i][1], t23 = h[i][2] + h[i][3];
      f16x2 t45 = h[i][4] + h[i][5], t67 = h[i][6] + h[i][7];
      f16x2 sum = (t01 + t23) + (t45 + t67);
      a0 = (float)sum[0];
      a1 = (float)sum[1];
    }
    // tail for deg > 8 (wave-uniform trip count; P ~ 15%)
    for (int p = s[i] + 8; p < e[i]; p += 8) {
      int id2[8];
#pragma unroll
      for (int j = 0; j < 8; ++j) {
        int pp = p + j;
        id2[j] = adj[pp < e[i] ? pp : e[i] - 1];
      }
      f16x2 g[8];
#pragma unroll
      for (int j = 0; j < 8; ++j) g[j] = *(const f16x2*)&base[(size_t)id2[j] * 128 + c0];
#pragma unroll
      for (int j = 0; j < 8; ++j) {
        f16x2 u = g[j];
        if (MODE) u = __builtin_elementwise_max(scv * u + sfv, zero);
        g[j] = (p + j < e[i]) ? u : zero;
      }
      f16x2 t01 = g[0] + g[1], t23 = g[2] + g[3];
      f16x2 t45 = g[4] + g[5], t67 = g[6] + g[7];
      f16x2 sum = (t01 + t23) + (t45 + t67);
      a0 += (float)sum[0];
      a1 += (float)sum[1];
    }
    f16x2 o;
    o[0] = (f16)a0;
    o[1] = (f16)a1;
    *(f16x2*)&xa[(size_t)(vbase + i) * 128 + c0] = o;
    if (MODE) {
      f16x2 yv = __builtin_elementwise_max(scv * own[i] + sfv, zero);
      *(f16x2*)&y[(size_t)(vbase + i) * 128 + c0] = yv;
    }
  }
}

// ----------------- fused GEMM: t = dinv * ([y|xa] @ Wcat^T + b0 + deg*b1); + BN stats -----
// 64 rows x 128 cols per block (1564 blocks), K=256 in 4 chunks of 64 halves.
// XOR-swizzled LDS (16B chunks), global_load_lds staging. t written as f16.
__global__ __launch_bounds__(256) void k_gemm(const f16* __restrict__ y, const f16* __restrict__ xa,
                                              const f16* __restrict__ Wc,
                                              const float* __restrict__ b0, const float* __restrict__ b1,
                                              const float* __restrict__ dinv, const float* __restrict__ degf,
                                              f16* __restrict__ tbuf, float* __restrict__ stats) {
  __shared__ __align__(16) f16 As[64 * 64];    // 512 x 16B chunks, chunk (r,c) at slot r*8 + (c^(r&7))
  __shared__ __align__(16) f16 Bs[128 * 64];   // 1024 x 16B chunks
  __shared__ float sstat[256];
  int tid = threadIdx.x;
  int w = tid >> 6, lane = tid & 63;
  int quad = lane >> 4, l16 = lane & 15;
  int row0 = blockIdx.x * 64;
  f32x4 acc[8] = {};
  sstat[tid] = 0.f;  // zeroed here; first __syncthreads below makes it visible

  for (int kc = 0; kc < 4; ++kc) {
    const f16* Abase = (kc < 2) ? y : xa;
    int koff = (kc & 1) * 64;
    // stage A: 512 chunks, 2 wave-instructions per wave
#pragma unroll
    for (int i = 0; i < 2; ++i) {
      int s = (w * 2 + i) * 64 + lane;
      int r = s >> 3, c = (s & 7) ^ (r & 7);
      GLD(Abase + (size_t)(row0 + r) * 128 + koff + c * 8, &As[(w * 2 + i) * 512]);
    }
    // stage B: 1024 chunks, 4 per wave
#pragma unroll
    for (int i = 0; i < 4; ++i) {
      int s = (w * 4 + i) * 64 + lane;
      int r = s >> 3, c = (s & 7) ^ (r & 7);
      GLD(Wc + (size_t)r * 256 + kc * 64 + c * 8, &Bs[(w * 4 + i) * 512]);
    }
    __syncthreads();  // drains vmcnt (global_load_lds) + barrier
#pragma unroll
    for (int ks = 0; ks < 2; ++ks) {
      int cc = ks * 4 + quad;
      int rr = w * 16 + l16;
      f16x8 af = *(const f16x8*)&As[(rr * 8 + (cc ^ (rr & 7))) * 8];
#pragma unroll
      for (int ni = 0; ni < 8; ++ni) {
        int rb = ni * 16 + l16;
        f16x8 bf = *(const f16x8*)&Bs[(rb * 8 + (cc ^ (rb & 7))) * 8];
        acc[ni] = __builtin_amdgcn_mfma_f32_16x16x32_f16(af, bf, acc[ni], 0, 0, 0);
      }
    }
    __syncthreads();
  }

  float b0c[8], b1c[8];
#pragma unroll
  for (int ni = 0; ni < 8; ++ni) {
    b0c[ni] = b0[ni * 16 + l16];
    b1c[ni] = b1[ni * 16 + l16];
  }
  float csum[8] = {}, csq[8] = {};
  // C/D layout: col = l16, row = quad*4 + reg
#pragma unroll
  for (int reg = 0; reg < 4; ++reg) {
    int v = row0 + w * 16 + quad * 4 + reg;
    if (v < V_N) {
      float dv = dinv[v], gf = degf[v];
#pragma unroll
      for (int ni = 0; ni < 8; ++ni) {
        float tv = dv * (acc[ni][reg] + b0c[ni] + gf * b1c[ni]);
        tbuf[(size_t)v * 128 + ni * 16 + l16] = (f16)tv;
        csum[ni] += tv;
        csq[ni] += tv * tv;
      }
    }
  }
#pragma unroll
  for (int ni = 0; ni < 8; ++ni) {
    csum[ni] += __shfl_xor(csum[ni], 16);
    csum[ni] += __shfl_xor(csum[ni], 32);
    csq[ni] += __shfl_xor(csq[ni], 16);
    csq[ni] += __shfl_xor(csq[ni], 32);
  }
  if (quad == 0) {
#pragma unroll
    for (int ni = 0; ni < 8; ++ni) {
      atomicAdd(&sstat[ni * 16 + l16], csum[ni]);
      atomicAdd(&sstat[128 + ni * 16 + l16], csq[ni]);
    }
  }
  __syncthreads();
  atomicAdd(&stats[(blockIdx.x & 63) * 256 + tid], sstat[tid]);  // 64-way sharded
}

__global__ void k_finalize(const float* __restrict__ stats, const float* __restrict__ gamma,
                           const float* __restrict__ beta, float* __restrict__ scale,
                           float* __restrict__ shift) {
  int d = threadIdx.x;  // 128
  float s = 0.f, sq = 0.f;
#pragma unroll 8
  for (int h = 0; h < 64; ++h) {
    s += stats[h * 256 + d];
    sq += stats[h * 256 + 128 + d];
  }
  float mu = s * (1.0f / V_N);
  float var = sq * (1.0f / V_N) - mu * mu;
  float scv = gamma[d] * rsqrtf(var + EPSV);
  scale[d] = scv;
  shift[d] = beta[d] - mu * scv;
}

// ----------------- final: out = relu(scale*t + shift + features) -----------------
__global__ __launch_bounds__(256) void k_final(const f16* __restrict__ t, const float* __restrict__ feat,
                                               const float* __restrict__ scale, const float* __restrict__ shift,
                                               float* __restrict__ out) {
  int q = blockIdx.x * 256 + threadIdx.x;  // float4 index
  if (q >= V_N * 32) return;
  int c4 = q & 31;
  f16x4 tv = *(const f16x4*)&t[(size_t)q * 4];
  float4 fv = ((const float4*)feat)[q];
  float4 sc = ((const float4*)scale)[c4];
  float4 sf = ((const float4*)shift)[c4];
  float4 o;
  o.x = fmaxf(sc.x * (float)tv[0] + sf.x + fv.x, 0.f);
  o.y = fmaxf(sc.y * (float)tv[1] + sf.y + fv.y, 0.f);
  o.z = fmaxf(sc.z * (float)tv[2] + sf.z + fv.z, 0.f);
  o.w = fmaxf(sc.w * (float)tv[3] + sf.w + fv.w, 0.f);
  ((float4*)out)[q] = o;
}

extern "C" void kernel_launch(void* const* d_in, const int* in_sizes, int n_in,
                              void* d_out, int out_size, void* d_ws, size_t ws_size,
                              hipStream_t stream) {
  const float* features = (const float*)d_in[0];
  const int* edges = (const int*)d_in[1];
  const float* W0 = (const float*)d_in[2];
  const float* b0 = (const float*)d_in[3];
  const float* W1 = (const float*)d_in[4];
  const float* b1 = (const float*)d_in[5];
  const float* gamma = (const float*)d_in[6];
  const float* beta = (const float*)d_in[7];
  float* out = (float*)d_out;

  char* ws = (char*)d_ws;
  size_t off = 0;
  auto alloc = [&](size_t bytes) -> void* {
    void* p = ws + off;
    off = (off + bytes + 255) & ~(size_t)255;
    return p;
  };
  int* deg = (int*)alloc((size_t)V_N * 4);
  int* csr_off = (int*)alloc((size_t)(V_N + 1) * 4);
  int* adj = (int*)alloc((size_t)2 * E_N * 4);
  float* dinv = (float*)alloc((size_t)V_N * 4);
  float* degf = (float*)alloc((size_t)V_N * 4);
  int* csum = (int*)alloc(512 * 4);
  int* coff = (int*)alloc(512 * 4);
  float* stats = (float*)alloc(64 * 256 * 4);
  float* scale = (float*)alloc(128 * 4);
  float* shift = (float*)alloc(128 * 4);
  f16* y = (f16*)alloc((size_t)MPAD * 128 * 2);
  f16* xa = (f16*)alloc((size_t)MPAD * 128 * 2);
  f16* tbuf = (f16*)alloc((size_t)MPAD * 128 * 2);
  f16* Wcat = (f16*)alloc((size_t)3 * 128 * 256 * 2);

  // CSR + dinv/degf
  hipMemsetAsync(deg, 0, (size_t)V_N * 4, stream);
  k_count<<<(2 * E_N + 255) / 256, 256, 0, stream>>>(edges, deg);
  k_chunksum<<<NCHUNK, 256, 0, stream>>>(deg, csum);
  k_scanchunks<<<1, 512, 0, stream>>>(csum, coff);
  k_writeoff<<<NCHUNK, 256, 0, stream>>>(deg, coff, csr_off, dinv, degf);
  hipMemsetAsync(deg, 0, (size_t)V_N * 4, stream);
  k_fill<<<(E_N + 255) / 256, 256, 0, stream>>>(edges, csr_off, deg, adj);
  k_prepw<<<384, 256, 0, stream>>>(W0, W1, Wcat);
  k_cast<<<12500, 256, 0, stream>>>(features, y);

  for (int l = 0; l < 3; ++l) {
    if (l == 0)
      k_gather<0><<<6250, 256, 0, stream>>>(tbuf, y, xa, csr_off, adj, scale, shift, stats);
    else
      k_gather<1><<<6250, 256, 0, stream>>>(tbuf, y, xa, csr_off, adj, scale, shift, stats);
    k_gemm<<<MPAD / 64, 256, 0, stream>>>(y, xa, Wcat + (size_t)l * 128 * 256, b0 + l * D_N,
                                          b1 + l * D_N, dinv, degf, tbuf, stats);
    k_finalize<<<1, 128, 0, stream>>>(stats, gamma + l * D_N, beta + l * D_N, scale, shift);
  }
  k_final<<<12500, 256, 0, stream>>>(tbuf, features, scale, shift, out);
}